// Round 1
// baseline (201.819 us; speedup 1.0000x reference)
//
#include <hip/hip_runtime.h>
#include <hip/hip_bf16.h>

// Problem constants
#define BATCH 256
#define CDIM  512
#define NPOS  49      // 7*7 attention positions
#define NPAD  64      // padded to 4 MFMA row-tiles
#define ASTRIDE 520   // a_lds row stride in bf16: 1040 B = 65*16 -> 16B-aligned rows, bank-balanced

typedef __attribute__((ext_vector_type(8))) short bf16x8_t;  // 8 bf16 (4 VGPRs) MFMA A/B frag
typedef __attribute__((ext_vector_type(4))) float f32x4_t;   // MFMA C/D frag

// ---------------------------------------------------------------------------
// Prep: convert Wa, Wh (fp32 [512][512]) to bf16 so the GEMM B-fragments are
// direct 16B loads. 1 MB output, L2-resident for the main kernel.
// ---------------------------------------------------------------------------
__global__ void prep_convert(const float* __restrict__ Wa,
                             const float* __restrict__ Wh,
                             __hip_bfloat16* __restrict__ Wab,
                             __hip_bfloat16* __restrict__ Whb) {
    int gid = blockIdx.x * blockDim.x + threadIdx.x;     // 0 .. 131071
    const int quarter = (CDIM * CDIM) / 4;               // 65536 float4 per matrix
    const float4* src;
    __hip_bfloat16* dst;
    int idx;
    if (gid < quarter) { src = (const float4*)Wa; dst = Wab; idx = gid; }
    else               { src = (const float4*)Wh; dst = Whb; idx = gid - quarter; }
    float4 v = src[idx];
    dst[idx * 4 + 0] = __float2bfloat16(v.x);
    dst[idx * 4 + 1] = __float2bfloat16(v.y);
    dst[idx * 4 + 2] = __float2bfloat16(v.z);
    dst[idx * 4 + 3] = __float2bfloat16(v.w);
}

// ---------------------------------------------------------------------------
// Main fused kernel: one workgroup per batch element b (grid 256 = 1 WG/CU).
// Phase 0: pool att_v[b] (2x2 mean) into a_lds [64 x 512] bf16 (rows=n, cols=c)
// Phase 1: MFMA GEMM  D[n][d] = sum_c a[n][c]*Wa[d][c] + sum_c h[c]*Wh[d][c]
//          (h-part: A rows identical -> broadcast frag from h_lds)
// Phase 2: scores[n] = sum_d tanh(D + ba[d] + bh[d]) * Wd[d]; softmax over 49;
//          att_res[c] = sum_n a[n][c]*w[n].  (bd dropped: softmax shift-inv.)
// ---------------------------------------------------------------------------
__global__ __launch_bounds__(512, 2) void att_spp_main(
    const float* __restrict__ att_v,          // [256,512,14,14]
    const float* __restrict__ h,              // [256,512]
    const float* __restrict__ ba,             // [512]
    const float* __restrict__ bh,             // [512]
    const float* __restrict__ Wd,             // [512]
    const __hip_bfloat16* __restrict__ Wab,   // [512][512] bf16
    const __hip_bfloat16* __restrict__ Whb,   // [512][512] bf16
    float* __restrict__ out)                  // [256,512]
{
    __shared__ __hip_bfloat16 a_lds[NPAD * ASTRIDE];  // 66,560 B
    __shared__ __hip_bfloat16 h_lds[CDIM];            // 1 KB
    __shared__ float babh_lds[CDIM];                  // ba+bh combined
    __shared__ float wd_lds[CDIM];
    __shared__ float scores_lds[NPAD];
    __shared__ float weights_lds[NPOS];

    const int b = blockIdx.x;
    const int t = threadIdx.x;

    // ---- Phase 0: stage vectors + pool ----
    h_lds[t]    = __float2bfloat16(h[b * CDIM + t]);
    babh_lds[t] = ba[t] + bh[t];
    wd_lds[t]   = Wd[t];
    if (t < NPAD) scores_lds[t] = 0.f;
    for (int idx = t; idx < (NPAD - NPOS) * ASTRIDE; idx += 512)
        a_lds[NPOS * ASTRIDE + idx] = __float2bfloat16(0.f);   // zero pad rows 49..63

    {
        // 8 lanes per channel-group: lane jj (0..6 active) covers float2 col-pair j,
        // group g (0..63) walks channels c = g + 64*ci.  Each input row = 56 B.
        const int jj = t & 7;
        const int g  = t >> 3;
        const float2* att2 = (const float2*)(att_v + (size_t)b * CDIM * 196);
        if (jj < 7) {
            for (int ci = 0; ci < 8; ++ci) {
                const int c = g + (ci << 6);
                const int cbase = c * 98;              // float2 units per channel
                #pragma unroll
                for (int i = 0; i < 7; ++i) {
                    float2 v0 = att2[cbase + i * 14 + jj];       // row 2i, cols 2j..2j+1
                    float2 v1 = att2[cbase + i * 14 + 7 + jj];   // row 2i+1
                    float p = (v0.x + v0.y + v1.x + v1.y) * 0.25f;
                    a_lds[(i * 7 + jj) * ASTRIDE + c] = __float2bfloat16(p);
                }
            }
        }
    }
    __syncthreads();

    // ---- Phase 1: MFMA GEMM ----
    const int wave = t >> 6;        // 0..7 -> cols [64*wave, 64*wave+64)
    const int lane = t & 63;
    const int q = lane >> 4;        // quad: k-offset q*8
    const int r = lane & 15;        // m (A rows) / n (B cols) within tile

    f32x4_t acc[4][4];              // [row-tile][col-tile]
    #pragma unroll
    for (int rt = 0; rt < 4; ++rt)
        #pragma unroll
        for (int ct = 0; ct < 4; ++ct)
            acc[rt][ct] = (f32x4_t){0.f, 0.f, 0.f, 0.f};

    const int dBase = wave * 64 + r;

    // part 1: k = 0..511  (a @ Wa^T)
    for (int ks = 0; ks < 16; ++ks) {
        const int k0 = ks * 32 + q * 8;
        bf16x8_t af[4];
        #pragma unroll
        for (int rt = 0; rt < 4; ++rt)
            af[rt] = *(const bf16x8_t*)&a_lds[(rt * 16 + r) * ASTRIDE + k0];
        bf16x8_t bf[4];
        #pragma unroll
        for (int ct = 0; ct < 4; ++ct)
            bf[ct] = *(const bf16x8_t*)&Wab[(size_t)(dBase + ct * 16) * CDIM + k0];
        #pragma unroll
        for (int rt = 0; rt < 4; ++rt)
            #pragma unroll
            for (int ct = 0; ct < 4; ++ct)
                acc[rt][ct] = __builtin_amdgcn_mfma_f32_16x16x32_bf16(
                    af[rt], bf[ct], acc[rt][ct], 0, 0, 0);
    }
    // part 2: k = 512..1023  (h @ Wh^T broadcast over n) — A frag same for all rows
    for (int ks = 0; ks < 16; ++ks) {
        const int k0 = ks * 32 + q * 8;
        bf16x8_t af = *(const bf16x8_t*)&h_lds[k0];
        bf16x8_t bf[4];
        #pragma unroll
        for (int ct = 0; ct < 4; ++ct)
            bf[ct] = *(const bf16x8_t*)&Whb[(size_t)(dBase + ct * 16) * CDIM + k0];
        #pragma unroll
        for (int rt = 0; rt < 4; ++rt)
            #pragma unroll
            for (int ct = 0; ct < 4; ++ct)
                acc[rt][ct] = __builtin_amdgcn_mfma_f32_16x16x32_bf16(
                    af, bf[ct], acc[rt][ct], 0, 0, 0);
    }

    // ---- Phase 2a: tanh + Wd-weighted reduction into scores ----
    // C/D layout: col = lane&15 (d), row = q*4 + reg (n within row-tile)
    float part[4][4];  // [rt][reg]
    #pragma unroll
    for (int rt = 0; rt < 4; ++rt)
        #pragma unroll
        for (int rg = 0; rg < 4; ++rg) part[rt][rg] = 0.f;

    #pragma unroll
    for (int ct = 0; ct < 4; ++ct) {
        const int d = dBase + ct * 16;
        const float bias = babh_lds[d];
        const float wd = wd_lds[d];
        #pragma unroll
        for (int rt = 0; rt < 4; ++rt)
            #pragma unroll
            for (int rg = 0; rg < 4; ++rg) {
                float x = acc[rt][ct][rg] + bias;
                float e = __expf(2.f * x);          // tanh = 1 - 2/(e^{2x}+1)
                part[rt][rg] += (1.f - 2.f / (e + 1.f)) * wd;
            }
    }
    // reduce over the 16 lanes (r bits 0..3) that share the same rows
    #pragma unroll
    for (int m = 1; m < 16; m <<= 1)
        #pragma unroll
        for (int rt = 0; rt < 4; ++rt)
            #pragma unroll
            for (int rg = 0; rg < 4; ++rg)
                part[rt][rg] += __shfl_xor(part[rt][rg], m, 64);
    if (r == 0) {
        #pragma unroll
        for (int rt = 0; rt < 4; ++rt)
            #pragma unroll
            for (int rg = 0; rg < 4; ++rg)
                atomicAdd(&scores_lds[rt * 16 + q * 4 + rg], part[rt][rg]);
    }
    __syncthreads();

    // ---- Phase 2b: softmax over 49 positions (wave 0) ----
    if (wave == 0) {
        float v = (lane < NPOS) ? scores_lds[lane] : -3.0e38f;
        float vmax = v;
        #pragma unroll
        for (int m = 1; m < 64; m <<= 1)
            vmax = fmaxf(vmax, __shfl_xor(vmax, m, 64));
        float e = (lane < NPOS) ? __expf(v - vmax) : 0.f;
        float s = e;
        #pragma unroll
        for (int m = 1; m < 64; m <<= 1)
            s += __shfl_xor(s, m, 64);
        if (lane < NPOS) weights_lds[lane] = e / s;
    }
    __syncthreads();

    // ---- Phase 2c: att_res[c] = sum_n a[n][c] * w[n] ----
    {
        float sum = 0.f;
        #pragma unroll
        for (int n = 0; n < NPOS; ++n)
            sum += __bfloat162float(a_lds[n * ASTRIDE + t]) * weights_lds[n];
        out[b * CDIM + t] = sum;
    }
}

extern "C" void kernel_launch(void* const* d_in, const int* in_sizes, int n_in,
                              void* d_out, int out_size, void* d_ws, size_t ws_size,
                              hipStream_t stream) {
    const float* att_v = (const float*)d_in[0];  // [256,512,14,14]
    const float* h     = (const float*)d_in[1];  // [256,512]
    const float* Wa    = (const float*)d_in[2];  // [512,512]
    const float* ba    = (const float*)d_in[3];  // [512]
    const float* Wh    = (const float*)d_in[4];  // [512,512]
    const float* bh    = (const float*)d_in[5];  // [512]
    const float* Wd    = (const float*)d_in[6];  // [512]
    // d_in[7] = bd: dropped (softmax is shift-invariant)

    __hip_bfloat16* Wab = (__hip_bfloat16*)d_ws;
    __hip_bfloat16* Whb = Wab + (size_t)CDIM * CDIM;

    prep_convert<<<512, 256, 0, stream>>>(Wa, Wh, Wab, Whb);
    att_spp_main<<<BATCH, 512, 0, stream>>>(att_v, h, ba, bh, Wd, Wab, Whb,
                                            (float*)d_out);
}